// Round 12
// baseline (99.259 us; speedup 1.0000x reference)
//
#include <hip/hip_runtime.h>

#define NCLS 7

// ws layout (4-byte slots):
//   [0] int   anchor   [1] int a_cls
//   [2] float pos_num  [3] float neg_num
//   [4] float inv_norm(anc_t) [5] inv_norm(anc_v) [6] inv_norm(anc_a)
//   [7]  pad
//   [8]  int  tail counter (zeroed by prep each call)
//   [9..15] pad
//   [16..]  per-row partials: float2 (pos, neg)
struct Hdr {
    int   anchor;
    int   a_cls;
    float pos_num;
    float neg_num;
    float inv_at;
    float inv_av;
    float inv_aa;
    int   pad;
};

__device__ __forceinline__ float dot4(float4 a, float4 b) {
    return a.x * b.x + a.y * b.y + a.z * b.z + a.w * b.w;
}

// ---- Wave64 reductions on the VALU pipe via DPP (no DS ops) ---------------
__device__ __forceinline__ float wave_fsum_dpp(float x) {
    float t;
    t = __int_as_float(__builtin_amdgcn_update_dpp(0, __float_as_int(x), 0x111, 0xf, 0xf, true));  x += t;
    t = __int_as_float(__builtin_amdgcn_update_dpp(0, __float_as_int(x), 0x112, 0xf, 0xf, true));  x += t;
    t = __int_as_float(__builtin_amdgcn_update_dpp(0, __float_as_int(x), 0x114, 0xf, 0xf, true));  x += t;
    t = __int_as_float(__builtin_amdgcn_update_dpp(0, __float_as_int(x), 0x118, 0xf, 0xf, true));  x += t;
    t = __int_as_float(__builtin_amdgcn_update_dpp(0, __float_as_int(x), 0x142, 0xa, 0xf, false)); x += t;
    t = __int_as_float(__builtin_amdgcn_update_dpp(0, __float_as_int(x), 0x143, 0xc, 0xf, false)); x += t;
    return __int_as_float(__builtin_amdgcn_readlane(__float_as_int(x), 63));
}

__device__ __forceinline__ int wave_isum_dpp(int x) {
    int t;
    t = __builtin_amdgcn_update_dpp(0, x, 0x111, 0xf, 0xf, true);  x += t;
    t = __builtin_amdgcn_update_dpp(0, x, 0x112, 0xf, 0xf, true);  x += t;
    t = __builtin_amdgcn_update_dpp(0, x, 0x114, 0xf, 0xf, true);  x += t;
    t = __builtin_amdgcn_update_dpp(0, x, 0x118, 0xf, 0xf, true);  x += t;
    t = __builtin_amdgcn_update_dpp(0, x, 0x142, 0xa, 0xf, false); x += t;
    t = __builtin_amdgcn_update_dpp(0, x, 0x143, 0xc, 0xf, false); x += t;
    return __builtin_amdgcn_readlane(x, 63);
}

__device__ __forceinline__ int wave_imin_dpp(int x) {
    const int I = 0x7fffffff;
    int t;
    t = __builtin_amdgcn_update_dpp(I, x, 0x111, 0xf, 0xf, false); x = min(x, t);
    t = __builtin_amdgcn_update_dpp(I, x, 0x112, 0xf, 0xf, false); x = min(x, t);
    t = __builtin_amdgcn_update_dpp(I, x, 0x114, 0xf, 0xf, false); x = min(x, t);
    t = __builtin_amdgcn_update_dpp(I, x, 0x118, 0xf, 0xf, false); x = min(x, t);
    t = __builtin_amdgcn_update_dpp(I, x, 0x142, 0xa, 0xf, false); x = min(x, t);
    t = __builtin_amdgcn_update_dpp(I, x, 0x143, 0xc, 0xf, false); x = min(x, t);
    return __builtin_amdgcn_readlane(x, 63);
}

// ---------------------------------------------------------------------------
// Kernel A (r9's fat prep, 1024 thr): labels pass (register histogram +
// per-class min, DPP reduce) THEN 12 waves compute the 3 anchor-row inverse
// norms (this beat computing them redundantly in main — r11 post-mortem).
// Also zeroes the tail counter for the fused finish.
// ---------------------------------------------------------------------------
__global__ __launch_bounds__(1024) void prep_kernel(
    const int* __restrict__ label,
    const float* __restrict__ s_t,
    const float* __restrict__ s_v,
    const float* __restrict__ s_a,
    int B, int D, float* __restrict__ ws)
{
    const int tid  = threadIdx.x;
    const int w    = tid >> 6;
    const int lane = tid & 63;

    int cnt[NCLS], mn[NCLS];
#pragma unroll
    for (int k = 0; k < NCLS; ++k) { cnt[k] = 0; mn[k] = 0x7fffffff; }

    const int4* lab4 = (const int4*)label;
    const int n4 = B >> 2;
    for (int j = tid; j < n4; j += 1024) {
        int4 L = lab4[j];
        const int base = j << 2;
        int ls[4] = { L.x, L.y, L.z, L.w };
#pragma unroll
        for (int e = 0; e < 4; ++e) {
#pragma unroll
            for (int k = 0; k < NCLS; ++k)
                if (ls[e] == k) { cnt[k]++; mn[k] = min(mn[k], base + e); }
        }
    }
    for (int i = (n4 << 2) + tid; i < B; i += 1024) {
        int l = label[i];
#pragma unroll
        for (int k = 0; k < NCLS; ++k)
            if (l == k) { cnt[k]++; mn[k] = min(mn[k], i); }
    }

#pragma unroll
    for (int k = 0; k < NCLS; ++k) {
        cnt[k] = wave_isum_dpp(cnt[k]);
        mn[k]  = wave_imin_dpp(mn[k]);
    }

    __shared__ int   s_cnt[16][NCLS], s_mn[16][NCLS];
    __shared__ int   s_anchor;
    __shared__ float s_norm[12];
    if (lane == 0) {
#pragma unroll
        for (int k = 0; k < NCLS; ++k) { s_cnt[w][k] = cnt[k]; s_mn[w][k] = mn[k]; }
    }
    __syncthreads();

    if (tid == 0) {
        int hist[NCLS], mini[NCLS];
#pragma unroll
        for (int k = 0; k < NCLS; ++k) {
            int hc = 0, mc = 0x7fffffff;
            for (int q = 0; q < 16; ++q) { hc += s_cnt[q][k]; mc = min(mc, s_mn[q][k]); }
            hist[k] = hc; mini[k] = mc;
        }
        // jnp.argmax(counts > 1): first class with count>1, else 0
        int c = 0;
#pragma unroll
        for (int k = NCLS - 1; k >= 0; --k) if (hist[k] > 1) c = k;
        s_anchor = mini[c];

        Hdr* h = (Hdr*)ws;
        h->anchor  = mini[c];
        h->a_cls   = c;
        float pn   = (float)hist[c];
        h->pos_num = pn;
        h->neg_num = (float)B - pn;
        ((int*)ws)[8] = 0;                 // tail counter for fused finish
    }
    __syncthreads();

    const int anchor = s_anchor;
    if (w < 12) {
        const int rw = w >> 2, qw = w & 3;
        const float* src = (rw == 0) ? s_t : (rw == 1) ? s_v : s_a;
        const float4* row = (const float4*)(src + (size_t)anchor * D);
        const int nvec = D >> 2;
        float s = 0.f;
        for (int j = qw * 64 + lane; j < nvec; j += 256) {
            float4 x = row[j];
            s += dot4(x, x);
        }
        s = wave_fsum_dpp(s);
        if (lane == 0) s_norm[w] = s;
    }
    __syncthreads();
    if (tid < 3)
        ((float*)ws)[4 + tid] = rsqrtf(s_norm[4 * tid] + s_norm[4 * tid + 1] +
                                       s_norm[4 * tid + 2] + s_norm[4 * tid + 3]);
}

// ---------------------------------------------------------------------------
// Kernel B: EXACT r9 hot path (one wave per row, zero LDS/DS, unroll-1,
// low VGPR, 8 waves/SIMD) + fused last-block finish (r4-proven pattern:
// store -> syncthreads(drains vmcnt) -> tid0 {threadfence, atomicAdd};
// last block: threadfence(invalidate) + fixed-order volatile reduce -> out).
// Deterministic: every block writes identical partials regardless of order;
// whichever block is last reads the complete array in a fixed order.
// ---------------------------------------------------------------------------
__global__ __launch_bounds__(256, 8) void main_kernel(
    const int* __restrict__ label,
    const float* __restrict__ s_t,
    const float* __restrict__ s_v,
    const float* __restrict__ s_a,
    int B, int D, float* __restrict__ ws, float* __restrict__ out)
{
    const Hdr* h = (const Hdr*)ws;
    float2* partials = (float2*)(ws + 16);
    int* counter = (int*)ws + 8;

    const int lane = threadIdx.x & 63;
    const int w    = threadIdx.x >> 6;
    const int r    = blockIdx.x * 4 + w;          // wave id == row

    if (r < B) {
        const int anchor = h->anchor;
        const int acls   = h->a_cls;
        const int lab    = label[r];

        const float4* rt = (const float4*)(s_t + (size_t)r * D);
        const float4* rv = (const float4*)(s_v + (size_t)r * D);
        const float4* ra = (const float4*)(s_a + (size_t)r * D);
        const float4* at = (const float4*)(s_t + (size_t)anchor * D);
        const float4* av = (const float4*)(s_v + (size_t)anchor * D);
        const float4* aa = (const float4*)(s_a + (size_t)anchor * D);

        float dt_a = 0.f, dt_v = 0.f, sq_t = 0.f;
        float dv_t = 0.f, dv_a = 0.f, sq_v = 0.f;
        float da_t = 0.f, da_v = 0.f, sq_a = 0.f;

        const int nvec = D >> 2;
#pragma unroll 1
        for (int j = lane; j < nvec; j += 64) {
            float4 t  = rt[j], v  = rv[j], a  = ra[j];
            float4 bt = at[j], bv = av[j], ba = aa[j];
            dt_a += dot4(t, ba);  dt_v += dot4(t, bv);  sq_t += dot4(t, t);
            dv_t += dot4(v, bt);  dv_a += dot4(v, ba);  sq_v += dot4(v, v);
            da_t += dot4(a, bt);  da_v += dot4(a, bv);  sq_a += dot4(a, a);
        }

        const float inv_t = rsqrtf(wave_fsum_dpp(sq_t));
        const float inv_v = rsqrtf(wave_fsum_dpp(sq_v));
        const float inv_a = rsqrtf(wave_fsum_dpp(sq_a));

        float c = inv_t * (dt_a * h->inv_aa + dt_v * h->inv_av)
                + inv_v * (dv_t * h->inv_at + dv_a * h->inv_aa)
                + inv_a * (da_t * h->inv_at + da_v * h->inv_av);
        const float rowtot = wave_fsum_dpp(c);

        if (lane == 0) {
            bool isPos = (lab == acls) && (r != anchor);
            bool isNeg = (lab != acls);
            partials[r] = make_float2(isPos ? rowtot : 0.f, isNeg ? rowtot : 0.f);
        }
    }

    // ---- fused finish: last-block-done ----
    __syncthreads();                       // drains vmcnt: stores are in L2
    __shared__ int s_last;
    if (threadIdx.x == 0) {
        __threadfence();                   // writeback: device-visible
        int old = atomicAdd(counter, 1);
        s_last = (old == (int)gridDim.x - 1);
    }
    __syncthreads();

    if (s_last) {
        __threadfence();                   // invalidate: see others' partials
        volatile float* pf = (volatile float*)partials;
        float p = 0.f, n = 0.f;
        for (int i = (int)threadIdx.x; i < B; i += 256) {
            p += pf[2 * i];
            n += pf[2 * i + 1];
        }
        p = wave_fsum_dpp(p);
        n = wave_fsum_dpp(n);
        __shared__ float pp[4], nn[4];
        if (lane == 0) { pp[w] = p; nn[w] = n; }
        __syncthreads();
        if (threadIdx.x == 0) {
            float P = pp[0] + pp[1] + pp[2] + pp[3];
            float N = nn[0] + nn[1] + nn[2] + nn[3];
            out[0] = (6.0f - P / h->pos_num + N / h->neg_num) / 3.0f;
        }
    }
}

extern "C" void kernel_launch(void* const* d_in, const int* in_sizes, int n_in,
                              void* d_out, int out_size, void* d_ws, size_t ws_size,
                              hipStream_t stream) {
    const int*   label = (const int*)d_in[0];
    const float* s_t   = (const float*)d_in[1];
    const float* s_v   = (const float*)d_in[2];
    const float* s_a   = (const float*)d_in[3];

    const int B = in_sizes[0];
    const int D = in_sizes[1] / B;   // 1024

    float* ws  = (float*)d_ws;
    float* out = (float*)d_out;

    const int nblocks = (B + 3) / 4;   // one wave per row, 4 waves per block

    prep_kernel<<<1, 1024, 0, stream>>>(label, s_t, s_v, s_a, B, D, ws);
    main_kernel<<<nblocks, 256, 0, stream>>>(label, s_t, s_v, s_a, B, D, ws, out);
}

// Round 14
// 29.215 us; speedup vs baseline: 3.3976x; 3.3976x over previous
//
#include <hip/hip_runtime.h>

#define NCLS 7

// ws layout (4-byte slots):
//   [0] int   anchor   [1] int a_cls
//   [2] float pos_num  [3] float neg_num
//   [4] float inv_norm(anc_t) [5] inv_norm(anc_v) [6] inv_norm(anc_a)
//   [7..15] pad
//   [16..]  per-row partials: float2 (pos, neg)
struct Hdr {
    int   anchor;
    int   a_cls;
    float pos_num;
    float neg_num;
    float inv_at;
    float inv_av;
    float inv_aa;
    int   pad;
};

// clang native vector type — required by __builtin_nontemporal_load
typedef float f4 __attribute__((ext_vector_type(4)));

__device__ __forceinline__ float dot4(float4 a, float4 b) {
    return a.x * b.x + a.y * b.y + a.z * b.z + a.w * b.w;
}
__device__ __forceinline__ float dot4n(f4 a, float4 b) {
    return a.x * b.x + a.y * b.y + a.z * b.z + a.w * b.w;
}
__device__ __forceinline__ float dot4nn(f4 a, f4 b) {
    return a.x * b.x + a.y * b.y + a.z * b.z + a.w * b.w;
}

// ---- Wave64 reductions on the VALU pipe via DPP (no DS ops) ---------------
__device__ __forceinline__ float wave_fsum_dpp(float x) {
    float t;
    t = __int_as_float(__builtin_amdgcn_update_dpp(0, __float_as_int(x), 0x111, 0xf, 0xf, true));  x += t;
    t = __int_as_float(__builtin_amdgcn_update_dpp(0, __float_as_int(x), 0x112, 0xf, 0xf, true));  x += t;
    t = __int_as_float(__builtin_amdgcn_update_dpp(0, __float_as_int(x), 0x114, 0xf, 0xf, true));  x += t;
    t = __int_as_float(__builtin_amdgcn_update_dpp(0, __float_as_int(x), 0x118, 0xf, 0xf, true));  x += t;
    t = __int_as_float(__builtin_amdgcn_update_dpp(0, __float_as_int(x), 0x142, 0xa, 0xf, false)); x += t;
    t = __int_as_float(__builtin_amdgcn_update_dpp(0, __float_as_int(x), 0x143, 0xc, 0xf, false)); x += t;
    return __int_as_float(__builtin_amdgcn_readlane(__float_as_int(x), 63));
}

__device__ __forceinline__ int wave_isum_dpp(int x) {
    int t;
    t = __builtin_amdgcn_update_dpp(0, x, 0x111, 0xf, 0xf, true);  x += t;
    t = __builtin_amdgcn_update_dpp(0, x, 0x112, 0xf, 0xf, true);  x += t;
    t = __builtin_amdgcn_update_dpp(0, x, 0x114, 0xf, 0xf, true);  x += t;
    t = __builtin_amdgcn_update_dpp(0, x, 0x118, 0xf, 0xf, true);  x += t;
    t = __builtin_amdgcn_update_dpp(0, x, 0x142, 0xa, 0xf, false); x += t;
    t = __builtin_amdgcn_update_dpp(0, x, 0x143, 0xc, 0xf, false); x += t;
    return __builtin_amdgcn_readlane(x, 63);
}

__device__ __forceinline__ int wave_imin_dpp(int x) {
    const int I = 0x7fffffff;
    int t;
    t = __builtin_amdgcn_update_dpp(I, x, 0x111, 0xf, 0xf, false); x = min(x, t);
    t = __builtin_amdgcn_update_dpp(I, x, 0x112, 0xf, 0xf, false); x = min(x, t);
    t = __builtin_amdgcn_update_dpp(I, x, 0x114, 0xf, 0xf, false); x = min(x, t);
    t = __builtin_amdgcn_update_dpp(I, x, 0x118, 0xf, 0xf, false); x = min(x, t);
    t = __builtin_amdgcn_update_dpp(I, x, 0x142, 0xa, 0xf, false); x = min(x, t);
    t = __builtin_amdgcn_update_dpp(I, x, 0x143, 0xc, 0xf, false); x = min(x, t);
    return __builtin_amdgcn_readlane(x, 63);
}

// ---------------------------------------------------------------------------
// Kernel A (r9's prep, 1024 thr): labels pass (register histogram + per-class
// min, DPP reduce), then 12 waves compute the 3 anchor-row inverse norms.
// ---------------------------------------------------------------------------
__global__ __launch_bounds__(1024) void prep_kernel(
    const int* __restrict__ label,
    const float* __restrict__ s_t,
    const float* __restrict__ s_v,
    const float* __restrict__ s_a,
    int B, int D, float* __restrict__ ws)
{
    const int tid  = threadIdx.x;
    const int w    = tid >> 6;
    const int lane = tid & 63;

    int cnt[NCLS], mn[NCLS];
#pragma unroll
    for (int k = 0; k < NCLS; ++k) { cnt[k] = 0; mn[k] = 0x7fffffff; }

    const int4* lab4 = (const int4*)label;
    const int n4 = B >> 2;
    for (int j = tid; j < n4; j += 1024) {
        int4 L = lab4[j];
        const int base = j << 2;
        int ls[4] = { L.x, L.y, L.z, L.w };
#pragma unroll
        for (int e = 0; e < 4; ++e) {
#pragma unroll
            for (int k = 0; k < NCLS; ++k)
                if (ls[e] == k) { cnt[k]++; mn[k] = min(mn[k], base + e); }
        }
    }
    for (int i = (n4 << 2) + tid; i < B; i += 1024) {
        int l = label[i];
#pragma unroll
        for (int k = 0; k < NCLS; ++k)
            if (l == k) { cnt[k]++; mn[k] = min(mn[k], i); }
    }

#pragma unroll
    for (int k = 0; k < NCLS; ++k) {
        cnt[k] = wave_isum_dpp(cnt[k]);
        mn[k]  = wave_imin_dpp(mn[k]);
    }

    __shared__ int   s_cnt[16][NCLS], s_mn[16][NCLS];
    __shared__ int   s_anchor;
    __shared__ float s_norm[12];
    if (lane == 0) {
#pragma unroll
        for (int k = 0; k < NCLS; ++k) { s_cnt[w][k] = cnt[k]; s_mn[w][k] = mn[k]; }
    }
    __syncthreads();

    if (tid == 0) {
        int hist[NCLS], mini[NCLS];
#pragma unroll
        for (int k = 0; k < NCLS; ++k) {
            int hc = 0, mc = 0x7fffffff;
            for (int q = 0; q < 16; ++q) { hc += s_cnt[q][k]; mc = min(mc, s_mn[q][k]); }
            hist[k] = hc; mini[k] = mc;
        }
        // jnp.argmax(counts > 1): first class with count>1, else 0
        int c = 0;
#pragma unroll
        for (int k = NCLS - 1; k >= 0; --k) if (hist[k] > 1) c = k;
        s_anchor = mini[c];

        Hdr* h = (Hdr*)ws;
        h->anchor  = mini[c];
        h->a_cls   = c;
        float pn   = (float)hist[c];
        h->pos_num = pn;
        h->neg_num = (float)B - pn;
    }
    __syncthreads();

    const int anchor = s_anchor;
    if (w < 12) {
        const int rw = w >> 2, qw = w & 3;
        const float* src = (rw == 0) ? s_t : (rw == 1) ? s_v : s_a;
        const float4* row = (const float4*)(src + (size_t)anchor * D);
        const int nvec = D >> 2;
        float s = 0.f;
        for (int j = qw * 64 + lane; j < nvec; j += 256) {
            float4 x = row[j];
            s += dot4(x, x);
        }
        s = wave_fsum_dpp(s);
        if (lane == 0) s_norm[w] = s;
    }
    __syncthreads();
    if (tid < 3)
        ((float*)ws)[4 + tid] = rsqrtf(s_norm[4 * tid] + s_norm[4 * tid + 1] +
                                       s_norm[4 * tid + 2] + s_norm[4 * tid + 3]);
}

// ---------------------------------------------------------------------------
// Kernel B: r9 hot path (one wave per row, zero LDS/DS, unroll-1, low VGPR,
// 8 waves/SIMD, NO tail — r12: barrier+fence tails collapse regalloc to
// 28 VGPR and serialize the loads). Own-row streams (touched once) use
// NONTEMPORAL loads (L1 bypass) via clang ext_vector_type pointers, so the
// 32 KB L1 holds only the anchor rows (12 KB, re-read by all 32 resident
// waves every iteration).
// ---------------------------------------------------------------------------
__global__ __launch_bounds__(256, 8) void main_kernel(
    const int* __restrict__ label,
    const float* __restrict__ s_t,
    const float* __restrict__ s_v,
    const float* __restrict__ s_a,
    int B, int D, float* __restrict__ ws)
{
    const Hdr* h = (const Hdr*)ws;
    float2* partials = (float2*)(ws + 16);

    const int lane = threadIdx.x & 63;
    const int r    = blockIdx.x * 4 + (threadIdx.x >> 6);   // wave id == row
    if (r >= B) return;

    const int anchor = h->anchor;
    const int acls   = h->a_cls;
    const int lab    = label[r];

    const f4* rt = (const f4*)(s_t + (size_t)r * D);
    const f4* rv = (const f4*)(s_v + (size_t)r * D);
    const f4* ra = (const f4*)(s_a + (size_t)r * D);
    const float4* at = (const float4*)(s_t + (size_t)anchor * D);
    const float4* av = (const float4*)(s_v + (size_t)anchor * D);
    const float4* aa = (const float4*)(s_a + (size_t)anchor * D);

    float dt_a = 0.f, dt_v = 0.f, sq_t = 0.f;
    float dv_t = 0.f, dv_a = 0.f, sq_v = 0.f;
    float da_t = 0.f, da_v = 0.f, sq_a = 0.f;

    const int nvec = D >> 2;
#pragma unroll 1
    for (int j = lane; j < nvec; j += 64) {
        f4 t = __builtin_nontemporal_load(&rt[j]);   // stream: L1 bypass
        f4 v = __builtin_nontemporal_load(&rv[j]);
        f4 a = __builtin_nontemporal_load(&ra[j]);
        float4 bt = at[j], bv = av[j], ba = aa[j];   // anchor: L1-resident
        dt_a += dot4n(t, ba);  dt_v += dot4n(t, bv);  sq_t += dot4nn(t, t);
        dv_t += dot4n(v, bt);  dv_a += dot4n(v, ba);  sq_v += dot4nn(v, v);
        da_t += dot4n(a, bt);  da_v += dot4n(a, bv);  sq_a += dot4nn(a, a);
    }

    const float inv_t = rsqrtf(wave_fsum_dpp(sq_t));
    const float inv_v = rsqrtf(wave_fsum_dpp(sq_v));
    const float inv_a = rsqrtf(wave_fsum_dpp(sq_a));

    float c = inv_t * (dt_a * h->inv_aa + dt_v * h->inv_av)
            + inv_v * (dv_t * h->inv_at + dv_a * h->inv_aa)
            + inv_a * (da_t * h->inv_at + da_v * h->inv_av);
    const float rowtot = wave_fsum_dpp(c);

    if (lane == 0) {
        bool isPos = (lab == acls) && (r != anchor);
        bool isNeg = (lab != acls);
        partials[r] = make_float2(isPos ? rowtot : 0.f, isNeg ? rowtot : 0.f);
    }
}

// ---------------------------------------------------------------------------
// Kernel C: deterministic reduction of B partial pairs -> scalar loss.
// loss = (6 - pos_total/pos_num + neg_total/neg_num) / 3
// ---------------------------------------------------------------------------
__global__ __launch_bounds__(1024) void finish_kernel(
    const float* __restrict__ ws, int B, float* __restrict__ out)
{
    const Hdr* h = (const Hdr*)ws;
    const float4* p4 = (const float4*)(ws + 16);   // (pos,neg,pos,neg)

    float p = 0.f, n = 0.f;
    const int n4 = B >> 1;                         // float4 count (B even)
    for (int j = threadIdx.x; j < n4; j += 1024) {
        float4 x = p4[j];
        p += x.x + x.z;
        n += x.y + x.w;
    }
    p = wave_fsum_dpp(p);
    n = wave_fsum_dpp(n);

    __shared__ float pp[16], nn[16];
    const int w = threadIdx.x >> 6, lane = threadIdx.x & 63;
    if (lane == 0) { pp[w] = p; nn[w] = n; }
    __syncthreads();
    if (threadIdx.x == 0) {
        float P = 0.f, N = 0.f;
#pragma unroll
        for (int k = 0; k < 16; ++k) { P += pp[k]; N += nn[k]; }
        out[0] = (6.0f - P / h->pos_num + N / h->neg_num) / 3.0f;
    }
}

extern "C" void kernel_launch(void* const* d_in, const int* in_sizes, int n_in,
                              void* d_out, int out_size, void* d_ws, size_t ws_size,
                              hipStream_t stream) {
    const int*   label = (const int*)d_in[0];
    const float* s_t   = (const float*)d_in[1];
    const float* s_v   = (const float*)d_in[2];
    const float* s_a   = (const float*)d_in[3];

    const int B = in_sizes[0];
    const int D = in_sizes[1] / B;   // 1024

    float* ws  = (float*)d_ws;
    float* out = (float*)d_out;

    const int nblocks = (B + 3) / 4;   // one wave per row, 4 waves per block

    prep_kernel<<<1, 1024, 0, stream>>>(label, s_t, s_v, s_a, B, D, ws);
    main_kernel<<<nblocks, 256, 0, stream>>>(label, s_t, s_v, s_a, B, D, ws);
    finish_kernel<<<1, 1024, 0, stream>>>(ws, B, out);
}